// Round 15
// baseline (576.199 us; speedup 1.0000x reference)
//
#include <hip/hip_runtime.h>
#include <hip/hip_bf16.h>
#include <cstdint>

typedef __bf16 bf16;
typedef __bf16 bf16x8 __attribute__((ext_vector_type(8)));
typedef float f32x4 __attribute__((ext_vector_type(4)));
typedef unsigned int u32;
typedef __attribute__((address_space(3))) uint32_t lds_u32;
typedef const __attribute__((address_space(1))) uint32_t glb_u32;

#define B_ 2
#define H_ 32
#define HKV_ 8
#define S_ 2048
#define D_ 128
#define QT 128                 // 128 q-rows/block, 8 waves
#define KT 64                  // 64-key tiles: K+V = 32 KB LDS -> 4 blocks/CU
#define NQT (S_ / QT)          // 16 q-tiles
#define NIMG (S_ / 64)         // 32 64-row ws images per (b,hkv)
#define IMG_ELEMS (64 * D_)    // 8192 bf16 = 16 KiB per ws image
#define NEG_BIG (-1.0e30f)
#define SCL 0.12751745f        // (1/sqrt(128)) * log2(e): softmax in exp2 domain
#define DEFER_THR 8.0f         // T13: skip O-rescale while max grows < 2^8

__device__ __forceinline__ bf16x8 cvt8p(float4 a, float4 b) {
  bf16x8 r = {(bf16)a.x, (bf16)a.y, (bf16)a.z, (bf16)a.w,
              (bf16)b.x, (bf16)b.y, (bf16)b.z, (bf16)b.w};
  return r;
}
__device__ __forceinline__ bf16x8 cvt8(const float* f) {
  return cvt8p(*(const float4*)f, *(const float4*)(f + 4));
}
__device__ __forceinline__ bf16x8 cvt8s(const float* f, float s) {
  float4 a = *(const float4*)f, b = *(const float4*)(f + 4);
  bf16x8 r = {(bf16)(a.x * s), (bf16)(a.y * s), (bf16)(a.z * s), (bf16)(a.w * s),
              (bf16)(b.x * s), (bf16)(b.y * s), (bf16)(b.z * s), (bf16)(b.w * s)};
  return r;
}
__device__ __forceinline__ u32 pk2(float lo, float hi) {  // plain casts (m240)
  union { bf16 h[2]; u32 w; } u;
  u.h[0] = (bf16)lo; u.h[1] = (bf16)hi;
  return u.w;
}

// ---------------- pre-pass: build swizzled bf16 LDS tile images in ws -------
// K image, per (bhkv,img): byte(row*256 + c16*16) holds K[row][(c16^(row&7))*8 ..+7]
// V image (transposed):    byte(d*128  + c8*16)  holds V[(c8^(d&7))*8 + t][d], t=0..7
__global__ __launch_bounds__(512) void prep(const float* __restrict__ k,
                                            const float* __restrict__ v,
                                            bf16* __restrict__ kws,
                                            bf16* __restrict__ vws) {
  __shared__ float Vf[64 * 129];  // stride 129: conflict-free column reads
  const int blk = blockIdx.x;     // 512 = 16 (b*hkv) * 32 images
  const int bhkv = blk >> 5, img = blk & 31;
  const float* ks = k + ((size_t)bhkv * S_ + (size_t)img * 64) * D_;
  const float* vs = v + ((size_t)bhkv * S_ + (size_t)img * 64) * D_;
  bf16* kd = kws + (size_t)blk * IMG_ELEMS;
  bf16* vd = vws + (size_t)blk * IMG_ELEMS;
  const int t = threadIdx.x;
#pragma unroll
  for (int i = 0; i < 4; ++i) {  // coalesced V tile -> LDS
    int c = t + 512 * i, row = c >> 5, c4 = c & 31;
    *(float4*)&Vf[row * 129 + c4 * 4] = *(const float4*)(vs + row * D_ + c4 * 4);
  }
#pragma unroll
  for (int i = 0; i < 2; ++i) {  // K image (coalesced read, linear write)
    int chunk = t + 512 * i, row = chunk >> 4, c16 = chunk & 15;
    int e = (c16 ^ (row & 7)) << 3;
    *(bf16x8*)&kd[chunk * 8] = cvt8(ks + row * D_ + e);
  }
  __syncthreads();
#pragma unroll
  for (int i = 0; i < 2; ++i) {  // V image from LDS transpose
    int chunk = t + 512 * i, d = chunk >> 3, c8 = chunk & 7;
    int k0 = (c8 ^ (d & 7)) << 3;
    bf16x8 val;
#pragma unroll
    for (int kk = 0; kk < 8; ++kk) val[kk] = (bf16)Vf[(k0 + kk) * 129 + d];
    *(bf16x8*)&vd[chunk * 8] = val;
  }
}

// ---------------- main: flash attention, QT=128 / KT=64 / 512 threads -------
// R15: max-residency configuration. T12 (no P LDS) + KT=64 with K AND V
// single-buffered -> 32 KB LDS/block; VGPR fits 64 -> launch_bounds(512,8):
// 4 blocks x 8 waves = 32 waves/CU (100% of slots), entire 1024-block grid
// resident at once -- barrier stalls of one block hidden by 3 others.
// tqt mapping balances per-CU load for round-robin assignment: quads
// {bid, bid+256, bid+512, bid+768} get tqts summing to 30.
// Sync/iter: QK ; [bar1 ; stageK(j+1)] ; softmax+T12 ; vmcnt(2)+bar2 ;
// PV ; [vmcnt(0)+bar3 ; stageV(j+1)].
// (R14's inline-asm permlane16_swap produced inf -- abandoned; reduces and
// P-redistribution use the R10-proven permlane32+shfl_xor+cndmask path.)
__global__ __launch_bounds__(512, 8) void fa_mfma(
    const float* __restrict__ q, const bf16* __restrict__ kws,
    const bf16* __restrict__ vws, float* __restrict__ out) {
  __shared__ bf16 Kb[IMG_ELEMS];  // 16 KiB: K tile [64 rows][128 d]
  __shared__ bf16 Vb[IMG_ELEMS];  // 16 KiB: V^T tile [128 d][64 keys]

  const int tid = threadIdx.x, wave = tid >> 6, lane = tid & 63;
  const int col = lane & 15, quad = lane >> 4;
  const int bid = blockIdx.x;
  // balanced-quad tqt mapping (see header comment)
  const int uu = bid >> 8, slot = (bid >> 6) & 3, tt = 4 * slot + uu;
  const int tqt = (tt & 1) ? (tt >> 1) : (NQT - 1) - (tt >> 1);
  const int bh = bid & 63, b = bh >> 5, h = bh & 31, hkv = h >> 2;  // GQA h/4
  const int bhkv = b * HKV_ + hkv;

  const float* qh = q + (size_t)(b * H_ + h) * S_ * D_;
  float* oh = out + (size_t)(b * H_ + h) * S_ * D_;
  const bf16* kg = kws + (size_t)(bhkv * NIMG) * IMG_ELEMS;
  const bf16* vg = vws + (size_t)(bhkv * NIMG) * IMG_ELEMS;
  const int q0 = tqt * QT;
  const int jmax = 2 * tqt + 1;  // 64-key tiles 0..jmax cover keys < q0+QT

  // Q fragments, pre-scaled by SCL (MFMA B-operand; same lane map as A)
  bf16x8 qf[4];
  {
    const float* qrow = qh + (size_t)(q0 + wave * 16 + col) * D_ + quad * 8;
#pragma unroll
    for (int ks = 0; ks < 4; ++ks) qf[ks] = cvt8s(qrow + ks * 32, SCL);
  }

  f32x4 o[8];  // O[qrow=col][d = dt*16 + quad*4 + r]
#pragma unroll
  for (int i = 0; i < 8; ++i) o[i] = (f32x4){0.f, 0.f, 0.f, 0.f};
  float m_i = NEG_BIG, lp = 0.f;  // scalar per lane (q-row = col)

  // swizzled-read offsets (same involution as prep)
  const int qoff = (quad * 16) ^ ((col & 7) << 4);  // < 128
  const int qx[4] = {qoff, qoff ^ 64, qoff ^ 128, qoff ^ 192};

  const int stoff = tid * 16;  // 512 threads x 16B = 8 KiB per pass

  auto stageK = [&](int j) {  // 2 gload_lds = 16 KiB tile
    const char* src = (const char*)kg + (size_t)j * 16384 + stoff;
    char* dst = (char*)Kb + stoff;
#pragma unroll
    for (int i = 0; i < 2; ++i)
      __builtin_amdgcn_global_load_lds((glb_u32*)(src + i * 8192),
                                       (lds_u32*)(dst + i * 8192), 16, 0, 0);
  };
  auto stageV = [&](int j) {
    const char* src = (const char*)vg + (size_t)j * 16384 + stoff;
    char* dst = (char*)Vb + stoff;
#pragma unroll
    for (int i = 0; i < 2; ++i)
      __builtin_amdgcn_global_load_lds((glb_u32*)(src + i * 8192),
                                       (lds_u32*)(dst + i * 8192), 16, 0, 0);
  };

  stageK(0);
  stageV(0);
  asm volatile("s_waitcnt vmcnt(0)" ::: "memory");
  __builtin_amdgcn_s_barrier();
  __builtin_amdgcn_sched_barrier(0);

  for (int j = 0; j <= jmax; ++j) {
    // ---- S strip, SWAPPED: s[nt][r] = S[key=nt*16+quad*4+r][qrow=col] ----
    float s[4][4];
    __builtin_amdgcn_s_setprio(1);
#pragma unroll
    for (int nt = 0; nt < 4; ++nt) {
      const char* An = (const char*)Kb + (nt * 16 + col) * 256;
      f32x4 acc = (f32x4){0.f, 0.f, 0.f, 0.f};
#pragma unroll
      for (int ks = 0; ks < 4; ++ks) {
        bf16x8 kf = *(const bf16x8*)(An + qx[ks]);
        acc = __builtin_amdgcn_mfma_f32_16x16x32_bf16(kf, qf[ks], acc, 0, 0, 0);
      }
#pragma unroll
      for (int r = 0; r < 4; ++r) s[nt][r] = acc[r];
    }
    __builtin_amdgcn_s_setprio(0);

    // bar1: Kb consumed by all waves -> restage it; DMA flies under
    // softmax+PV of this iteration
    if (j < jmax) {
      __builtin_amdgcn_s_barrier();
      __builtin_amdgcn_sched_barrier(0);
      stageK(j + 1);
    }

    // causal mask: only the last two k-tiles intersect the diagonal
    if (j >= 2 * tqt) {
      const int rel = j * KT - q0 - wave * 16;
#pragma unroll
      for (int nt = 0; nt < 4; ++nt)
#pragma unroll
        for (int r = 0; r < 4; ++r)
          if (rel + nt * 16 + quad * 4 + r > col) s[nt][r] = NEG_BIG;
    }

    // ---- softmax: lane-local max over 16 + 2 quad-reduce shuffles ----
    float mx = fmaxf(fmaxf(fmaxf(s[0][0], s[0][1]), fmaxf(s[0][2], s[0][3])),
                     fmaxf(fmaxf(s[1][0], s[1][1]), fmaxf(s[1][2], s[1][3])));
    mx = fmaxf(mx,
               fmaxf(fmaxf(fmaxf(s[2][0], s[2][1]), fmaxf(s[2][2], s[2][3])),
                     fmaxf(fmaxf(s[3][0], s[3][1]), fmaxf(s[3][2], s[3][3]))));
    mx = fmaxf(mx, __shfl_xor(mx, 16, 64));
    mx = fmaxf(mx, __shfl_xor(mx, 32, 64));  // uniform across quads @ col

    if (__any(mx - m_i > DEFER_THR)) {  // T13 defer-max
      float mnew = fmaxf(m_i, mx);
      float alpha = exp2f(m_i - mnew);
      lp *= alpha;
      m_i = mnew;
#pragma unroll
      for (int dt = 0; dt < 8; ++dt) o[dt] *= alpha;
    }

    float rs = 0.f;
#pragma unroll
    for (int nt = 0; nt < 4; ++nt)
#pragma unroll
      for (int r = 0; r < 4; ++r) {
        s[nt][r] = exp2f(s[nt][r] - m_i);  // bounded by 2^THR
        rs += s[nt][r];
      }
    lp += rs;

    // ---- P -> PV B-operand, in-register (T12, R10-proven path) ----
    u32 pk_[4][2];
#pragma unroll
    for (int nt = 0; nt < 4; ++nt) {
      pk_[nt][0] = pk2(s[nt][0], s[nt][1]);
      pk_[nt][1] = pk2(s[nt][2], s[nt][3]);
    }
    const bool oddq = (quad & 1);
    union W8 { u32 w[4]; bf16x8 h; } pf[2];
#pragma unroll
    for (int ks = 0; ks < 2; ++ks)
#pragma unroll
      for (int p = 0; p < 2; ++p) {
        auto sw = __builtin_amdgcn_permlane32_swap(pk_[2 * ks][p],
                                                   pk_[2 * ks + 1][p],
                                                   false, false);
        u32 Qp = (u32)sw[0], Rp = (u32)sw[1];
        u32 Tp = (u32)__shfl_xor((int)Qp, 16, 64);
        u32 Sp = (u32)__shfl_xor((int)Rp, 16, 64);
        pf[ks].w[p] = oddq ? Sp : Qp;      // words 0,1
        pf[ks].w[2 + p] = oddq ? Rp : Tp;  // words 2,3
      }

    // bar2 (counted): V(j)'s 2 loads (oldest) retired; K(j+1)'s 2 in flight
    if (j < jmax)
      asm volatile("s_waitcnt vmcnt(2)" ::: "memory");
    else
      asm volatile("s_waitcnt vmcnt(0)" ::: "memory");
    __builtin_amdgcn_s_barrier();
    __builtin_amdgcn_sched_barrier(0);

    // ---- O += V^T·P (swapped): o[dt] rows = d, cols = qrow ----
    __builtin_amdgcn_s_setprio(1);
#pragma unroll
    for (int dt = 0; dt < 8; ++dt) {
      const char* Av = (const char*)Vb + (dt * 16 + col) * 128;
#pragma unroll
      for (int ks = 0; ks < 2; ++ks) {
        bf16x8 vf = *(const bf16x8*)(Av + qx[ks]);
        o[dt] = __builtin_amdgcn_mfma_f32_16x16x32_bf16(vf, pf[ks].h, o[dt], 0, 0, 0);
      }
    }
    __builtin_amdgcn_s_setprio(0);

    // bar3: K(j+1) landed + all Vb reads done -> restage V
    if (j < jmax) {
      asm volatile("s_waitcnt vmcnt(0)" ::: "memory");
      __builtin_amdgcn_s_barrier();
      __builtin_amdgcn_sched_barrier(0);
      stageV(j + 1);  // DMA flies under next iteration's QK+softmax
    }
  }

  // ---- epilogue: l quad-reduce (2 shfl), O/l, float4 stores ----
  float l = lp;
  l += __shfl_xor(l, 16, 64);
  l += __shfl_xor(l, 32, 64);
  const float inv = 1.f / l;
  float* orow = oh + (size_t)(q0 + wave * 16 + col) * D_;
#pragma unroll
  for (int dt = 0; dt < 8; ++dt) {
    f32x4 vout = o[dt] * inv;
    *(f32x4*)&orow[dt * 16 + quad * 4] = vout;
  }
}

extern "C" void kernel_launch(void* const* d_in, const int* in_sizes, int n_in,
                              void* d_out, int out_size, void* d_ws, size_t ws_size,
                              hipStream_t stream) {
  const int QN = B_ * H_ * S_ * D_;
  int qi, ki, vi;
  if (in_sizes[0] == QN)      { qi = 0; ki = 1; vi = 2; }
  else if (in_sizes[1] == QN) { qi = 1; ki = 0; vi = 2; }
  else                        { qi = 2; ki = 0; vi = 1; }
  const float* q = (const float*)d_in[qi];
  const float* k = (const float*)d_in[ki];
  const float* v = (const float*)d_in[vi];
  float* out = (float*)d_out;

  // ws: K images then V images; 2 * 16*32*8192 bf16 = 16 MiB total
  bf16* kws = (bf16*)d_ws;
  bf16* vws = kws + (size_t)(B_ * HKV_) * NIMG * IMG_ELEMS;

  prep<<<dim3(B_ * HKV_ * NIMG), dim3(512), 0, stream>>>(k, v, kws, vws);
  fa_mfma<<<dim3(B_ * H_ * NQT), dim3(512), 0, stream>>>(q, kws, vws, out);
}

// Round 16
// 237.900 us; speedup vs baseline: 2.4220x; 2.4220x over previous
//
#include <hip/hip_runtime.h>
#include <hip/hip_bf16.h>
#include <cstdint>

typedef __bf16 bf16;
typedef __bf16 bf16x8 __attribute__((ext_vector_type(8)));
typedef float f32x4 __attribute__((ext_vector_type(4)));
typedef unsigned int u32;
typedef __attribute__((address_space(3))) uint32_t lds_u32;
typedef const __attribute__((address_space(1))) uint32_t glb_u32;

#if defined(__has_builtin)
#if __has_builtin(__builtin_amdgcn_permlane16_swap)
#define HAVE_PL16 1
#endif
#endif

#define B_ 2
#define H_ 32
#define HKV_ 8
#define S_ 2048
#define D_ 128
#define QT 128                 // 128 q-rows/block, 8 waves
#define KT 128                 // 128-key tiles (2 ws images per tile)
#define NQT (S_ / QT)          // 16 q-tiles
#define NIMG (S_ / 64)         // 32 64-row ws images per (b,hkv)
#define IMG_ELEMS (64 * D_)    // 8192 bf16 = 16 KiB per ws image
#define NEG_BIG (-1.0e30f)
#define SCL 0.12751745f        // (1/sqrt(128)) * log2(e): softmax in exp2 domain
#define DEFER_THR 8.0f         // T13: skip O-rescale while max grows < 2^8

__device__ __forceinline__ bf16x8 cvt8p(float4 a, float4 b) {
  bf16x8 r = {(bf16)a.x, (bf16)a.y, (bf16)a.z, (bf16)a.w,
              (bf16)b.x, (bf16)b.y, (bf16)b.z, (bf16)b.w};
  return r;
}
__device__ __forceinline__ bf16x8 cvt8(const float* f) {
  return cvt8p(*(const float4*)f, *(const float4*)(f + 4));
}
__device__ __forceinline__ bf16x8 cvt8s(const float* f, float s) {
  float4 a = *(const float4*)f, b = *(const float4*)(f + 4);
  bf16x8 r = {(bf16)(a.x * s), (bf16)(a.y * s), (bf16)(a.z * s), (bf16)(a.w * s),
              (bf16)(b.x * s), (bf16)(b.y * s), (bf16)(b.z * s), (bf16)(b.w * s)};
  return r;
}
__device__ __forceinline__ u32 pk2(float lo, float hi) {  // plain casts (m240)
  union { bf16 h[2]; u32 w; } u;
  u.h[0] = (bf16)lo; u.h[1] = (bf16)hi;
  return u.w;
}

// ---------------- pre-pass: build swizzled bf16 LDS tile images in ws -------
// K image, per (bhkv,img): byte(row*256 + c16*16) holds K[row][(c16^(row&7))*8 ..+7]
// V image (transposed):    byte(d*128  + c8*16)  holds V[(c8^(d&7))*8 + t][d], t=0..7
__global__ __launch_bounds__(512) void prep(const float* __restrict__ k,
                                            const float* __restrict__ v,
                                            bf16* __restrict__ kws,
                                            bf16* __restrict__ vws) {
  __shared__ float Vf[64 * 129];  // stride 129: conflict-free column reads
  const int blk = blockIdx.x;     // 512 = 16 (b*hkv) * 32 images
  const int bhkv = blk >> 5, img = blk & 31;
  const float* ks = k + ((size_t)bhkv * S_ + (size_t)img * 64) * D_;
  const float* vs = v + ((size_t)bhkv * S_ + (size_t)img * 64) * D_;
  bf16* kd = kws + (size_t)blk * IMG_ELEMS;
  bf16* vd = vws + (size_t)blk * IMG_ELEMS;
  const int t = threadIdx.x;
#pragma unroll
  for (int i = 0; i < 4; ++i) {  // coalesced V tile -> LDS
    int c = t + 512 * i, row = c >> 5, c4 = c & 31;
    *(float4*)&Vf[row * 129 + c4 * 4] = *(const float4*)(vs + row * D_ + c4 * 4);
  }
#pragma unroll
  for (int i = 0; i < 2; ++i) {  // K image (coalesced read, linear write)
    int chunk = t + 512 * i, row = chunk >> 4, c16 = chunk & 15;
    int e = (c16 ^ (row & 7)) << 3;
    *(bf16x8*)&kd[chunk * 8] = cvt8(ks + row * D_ + e);
  }
  __syncthreads();
#pragma unroll
  for (int i = 0; i < 2; ++i) {  // V image from LDS transpose
    int chunk = t + 512 * i, d = chunk >> 3, c8 = chunk & 7;
    int k0 = (c8 ^ (d & 7)) << 3;
    bf16x8 val;
#pragma unroll
    for (int kk = 0; kk < 8; ++kk) val[kk] = (bf16)Vf[(k0 + kk) * 129 + d];
    *(bf16x8*)&vd[chunk * 8] = val;
  }
}

// ---------------- main: flash attention, QT=128 / KT=128 / 512 threads ------
// R16 = R13 (140us proven: KT=128, (512,4), LPT) + P-redistribution via the
// permlane16_swap BUILTIN (not R14's aliasing-prone inline asm), guarded by
// __has_builtin (missing builtin -> exact R13 fallback). pl32(A,C)=(Q,R) then
// pl16(Q,R) = ([A0,A2,C0,C2],[A1,A3,C1,C3]) = words w0/w2 directly for all
// quads -- deletes 16 DS-shuffles + 16 cndmask from the softmax->PV chain.
// R15 lesson (measured twice, R8+R15): kernel needs ~96 unified regs (64 VGPR
// + 32 AGPR o[]); >4 waves/SIMD via launch_bounds forces catastrophic spill.
__global__ __launch_bounds__(512, 4) void fa_mfma(
    const float* __restrict__ q, const bf16* __restrict__ kws,
    const bf16* __restrict__ vws, float* __restrict__ out) {
  __shared__ bf16 Kb[2 * IMG_ELEMS];  // 32 KiB: K tile [128 rows][128 d]
  __shared__ bf16 Vb[2 * IMG_ELEMS];  // 32 KiB: V^T tile, 2 key-half images

  const int tid = threadIdx.x, wave = tid >> 6, lane = tid & 63;
  const int col = lane & 15, quad = lane >> 4;
  const int bid = blockIdx.x;
  const int tqt = (NQT - 1) - (bid >> 6);  // LPT: longest blocks first
  const int bh = bid & 63, b = bh >> 5, h = bh & 31, hkv = h >> 2;  // GQA h/4
  const int bhkv = b * HKV_ + hkv;

  const float* qh = q + (size_t)(b * H_ + h) * S_ * D_;
  float* oh = out + (size_t)(b * H_ + h) * S_ * D_;
  const bf16* kg = kws + (size_t)(bhkv * NIMG) * IMG_ELEMS;
  const bf16* vg = vws + (size_t)(bhkv * NIMG) * IMG_ELEMS;
  const int q0 = tqt * QT;
  const int jmax = tqt;  // 128-key tiles 0..tqt cover keys < q0+QT

  // Q fragments, pre-scaled by SCL (MFMA B-operand; same lane map as A)
  bf16x8 qf[4];
  {
    const float* qrow = qh + (size_t)(q0 + wave * 16 + col) * D_ + quad * 8;
#pragma unroll
    for (int ks = 0; ks < 4; ++ks) qf[ks] = cvt8s(qrow + ks * 32, SCL);
  }

  f32x4 o[8];  // O[qrow=col][d = dt*16 + quad*4 + r]
#pragma unroll
  for (int i = 0; i < 8; ++i) o[i] = (f32x4){0.f, 0.f, 0.f, 0.f};
  float m_i = NEG_BIG, lp = 0.f;  // scalar per lane (q-row = col)

  // swizzled-read offsets (same involution as prep)
  const int qoff = (quad * 16) ^ ((col & 7) << 4);  // < 128
  const int qx[4] = {qoff, qoff ^ 64, qoff ^ 128, qoff ^ 192};

  const int stoff = tid * 16;  // 512 threads x 16B = 8 KiB per pass

  auto stageK = [&](int j) {  // 4 gload_lds = 32 KiB tile
    const char* src = (const char*)kg + (size_t)j * 32768 + stoff;
    char* dst = (char*)Kb + stoff;
#pragma unroll
    for (int i = 0; i < 4; ++i)
      __builtin_amdgcn_global_load_lds((glb_u32*)(src + i * 8192),
                                       (lds_u32*)(dst + i * 8192), 16, 0, 0);
  };
  auto stageV = [&](int j) {
    const char* src = (const char*)vg + (size_t)j * 32768 + stoff;
    char* dst = (char*)Vb + stoff;
#pragma unroll
    for (int i = 0; i < 4; ++i)
      __builtin_amdgcn_global_load_lds((glb_u32*)(src + i * 8192),
                                       (lds_u32*)(dst + i * 8192), 16, 0, 0);
  };

  stageK(0);
  stageV(0);
  asm volatile("s_waitcnt vmcnt(0)" ::: "memory");
  __builtin_amdgcn_s_barrier();
  __builtin_amdgcn_sched_barrier(0);

  for (int j = 0; j <= jmax; ++j) {
    // ---- S strip, SWAPPED: s[nt][r] = S[key=nt*16+quad*4+r][qrow=col] ----
    float s[8][4];
    __builtin_amdgcn_s_setprio(1);
#pragma unroll
    for (int nt = 0; nt < 8; ++nt) {
      const char* An = (const char*)Kb + (nt * 16 + col) * 256;
      f32x4 acc = (f32x4){0.f, 0.f, 0.f, 0.f};
#pragma unroll
      for (int ks = 0; ks < 4; ++ks) {
        bf16x8 kf = *(const bf16x8*)(An + qx[ks]);
        acc = __builtin_amdgcn_mfma_f32_16x16x32_bf16(kf, qf[ks], acc, 0, 0, 0);
      }
#pragma unroll
      for (int r = 0; r < 4; ++r) s[nt][r] = acc[r];
    }
    __builtin_amdgcn_s_setprio(0);

    // bar1: all waves consumed Kb -> safe to restage; K(j+1) DMA flies
    __builtin_amdgcn_s_barrier();
    __builtin_amdgcn_sched_barrier(0);
    if (j < jmax) stageK(j + 1);

    // causal mask: only the diagonal tile (key base == q base)
    if (j == tqt) {
      const int rowq = wave * 16 + col;
#pragma unroll
      for (int nt = 0; nt < 8; ++nt)
#pragma unroll
        for (int r = 0; r < 4; ++r)
          if (nt * 16 + quad * 4 + r > rowq) s[nt][r] = NEG_BIG;
    }

    // ---- softmax: lane-local max over 32 + 2 quad-reduce shuffles ----
    float m4[8];
#pragma unroll
    for (int nt = 0; nt < 8; ++nt)
      m4[nt] = fmaxf(fmaxf(s[nt][0], s[nt][1]), fmaxf(s[nt][2], s[nt][3]));
    float mx = fmaxf(fmaxf(fmaxf(m4[0], m4[1]), fmaxf(m4[2], m4[3])),
                     fmaxf(fmaxf(m4[4], m4[5]), fmaxf(m4[6], m4[7])));
    mx = fmaxf(mx, __shfl_xor(mx, 16, 64));
    mx = fmaxf(mx, __shfl_xor(mx, 32, 64));  // uniform across quads @ col

    if (__any(mx - m_i > DEFER_THR)) {  // T13 defer-max
      float mnew = fmaxf(m_i, mx);
      float alpha = exp2f(m_i - mnew);
      lp *= alpha;
      m_i = mnew;
#pragma unroll
      for (int dt = 0; dt < 8; ++dt) o[dt] *= alpha;
    }

    float rs = 0.f;
#pragma unroll
    for (int nt = 0; nt < 8; ++nt)
#pragma unroll
      for (int r = 0; r < 4; ++r) {
        s[nt][r] = exp2f(s[nt][r] - m_i);  // bounded by 2^THR
        rs += s[nt][r];
      }
    lp += rs;

    // ---- P -> PV B-operand, in-register (T12) ----
    u32 pk_[8][2];
#pragma unroll
    for (int nt = 0; nt < 8; ++nt) {
      pk_[nt][0] = pk2(s[nt][0], s[nt][1]);
      pk_[nt][1] = pk2(s[nt][2], s[nt][3]);
    }
    union W8 { u32 w[4]; bf16x8 h; } pf[4];
#ifdef HAVE_PL16
    // pl32(A,C) -> Q=[A0,A1,C0,C1], R=[A2,A3,C2,C3] (16-lane rows);
    // pl16(Q,R) -> ([Q0,R0,Q2,R2],[Q1,R1,Q3,R3]) = ([A0,A2,C0,C2],
    // [A1,A3,C1,C3]) = w0/w2 (p=0) resp. w1/w3 (p=1), uniform over quads.
#pragma unroll
    for (int ks = 0; ks < 4; ++ks)
#pragma unroll
      for (int p = 0; p < 2; ++p) {
        auto s1 = __builtin_amdgcn_permlane32_swap(pk_[2 * ks][p],
                                                   pk_[2 * ks + 1][p],
                                                   false, false);
        auto s2 = __builtin_amdgcn_permlane16_swap((u32)s1[0], (u32)s1[1],
                                                   false, false);
        pf[ks].w[p] = (u32)s2[0];      // w0 (p=0) / w1 (p=1)
        pf[ks].w[2 + p] = (u32)s2[1];  // w2 (p=0) / w3 (p=1)
      }
#else
    const bool oddq = (quad & 1);
#pragma unroll
    for (int ks = 0; ks < 4; ++ks)
#pragma unroll
      for (int p = 0; p < 2; ++p) {
        auto sw = __builtin_amdgcn_permlane32_swap(pk_[2 * ks][p],
                                                   pk_[2 * ks + 1][p],
                                                   false, false);
        u32 Qp = (u32)sw[0], Rp = (u32)sw[1];
        u32 Tp = (u32)__shfl_xor((int)Qp, 16, 64);
        u32 Sp = (u32)__shfl_xor((int)Rp, 16, 64);
        pf[ks].w[p] = oddq ? Sp : Qp;      // words 0,1
        pf[ks].w[2 + p] = oddq ? Rp : Tp;  // words 2,3
      }
#endif

    // bar2 (counted): V(j) landed for all waves; K(j+1)'s 4 loads in flight
    if (j < jmax)
      asm volatile("s_waitcnt vmcnt(4)" ::: "memory");
    else
      asm volatile("s_waitcnt vmcnt(0)" ::: "memory");
    __builtin_amdgcn_s_barrier();
    __builtin_amdgcn_sched_barrier(0);

    // ---- O += V^T·P (swapped): key-half image select = (ks>>1)*16384 ----
    __builtin_amdgcn_s_setprio(1);
#pragma unroll
    for (int dt = 0; dt < 8; ++dt) {
#pragma unroll
      for (int ks = 0; ks < 4; ++ks) {
        const char* Av = (const char*)Vb + (ks >> 1) * 16384 +
                         (dt * 16 + col) * 128 + (qoff ^ ((ks & 1) << 6));
        bf16x8 vf = *(const bf16x8*)Av;
        o[dt] = __builtin_amdgcn_mfma_f32_16x16x32_bf16(vf, pf[ks].h, o[dt], 0, 0, 0);
      }
    }
    __builtin_amdgcn_s_setprio(0);

    // bar3: K(j+1) drained (covered by PV) + Vb reads done -> restage V
    if (j < jmax) {
      asm volatile("s_waitcnt vmcnt(0)" ::: "memory");
      __builtin_amdgcn_s_barrier();
      __builtin_amdgcn_sched_barrier(0);
      stageV(j + 1);  // DMA flies under next iteration's QK+softmax
    }
  }

  // ---- epilogue: l quad-reduce (2 shfl), O/l, float4 stores ----
  float l = lp;
  l += __shfl_xor(l, 16, 64);
  l += __shfl_xor(l, 32, 64);
  const float inv = 1.f / l;
  float* orow = oh + (size_t)(q0 + wave * 16 + col) * D_;
#pragma unroll
  for (int dt = 0; dt < 8; ++dt) {
    f32x4 vout = o[dt] * inv;
    *(f32x4*)&orow[dt * 16 + quad * 4] = vout;
  }
}

extern "C" void kernel_launch(void* const* d_in, const int* in_sizes, int n_in,
                              void* d_out, int out_size, void* d_ws, size_t ws_size,
                              hipStream_t stream) {
  const int QN = B_ * H_ * S_ * D_;
  int qi, ki, vi;
  if (in_sizes[0] == QN)      { qi = 0; ki = 1; vi = 2; }
  else if (in_sizes[1] == QN) { qi = 1; ki = 0; vi = 2; }
  else                        { qi = 2; ki = 0; vi = 1; }
  const float* q = (const float*)d_in[qi];
  const float* k = (const float*)d_in[ki];
  const float* v = (const float*)d_in[vi];
  float* out = (float*)d_out;

  // ws: K images then V images; 2 * 16*32*8192 bf16 = 16 MiB total
  bf16* kws = (bf16*)d_ws;
  bf16* vws = kws + (size_t)(B_ * HKV_) * NIMG * IMG_ELEMS;

  prep<<<dim3(B_ * HKV_ * NIMG), dim3(512), 0, stream>>>(k, v, kws, vws);
  fa_mfma<<<dim3(B_ * H_ * NQT), dim3(512), 0, stream>>>(q, kws, vws, out);
}